// Round 2
// baseline (2059.166 us; speedup 1.0000x reference)
//
#include <hip/hip_runtime.h>
#include <hip/hip_bf16.h>

// All reference dtypes are float32: inputs are const float*, output is float*.

// C[M,N] = A[M,K] @ W[N,K]^T + bias[N]
// BM=BN=64, BK=16, 256 threads, each thread computes a 4x4 micro-tile.
__global__ void gemm_bt_kernel(const float* __restrict__ A, const float* __restrict__ W,
                               const float* __restrict__ bias, float* __restrict__ C,
                               int M, int N, int K) {
    const int BM = 64, BN = 64, BK = 16;
    __shared__ float As[BK][BM + 1];
    __shared__ float Ws[BK][BN + 1];
    const int tid = threadIdx.x;
    const int tx = tid % 16, ty = tid / 16;
    const int m0 = blockIdx.y * BM, n0 = blockIdx.x * BN;
    float acc[4][4] = {};

    for (int k0 = 0; k0 < K; k0 += BK) {
        for (int idx = tid; idx < BM * BK; idx += 256) {
            int m = idx / BK, kk = idx % BK;
            As[kk][m] = A[(size_t)(m0 + m) * K + k0 + kk];
        }
        for (int idx = tid; idx < BN * BK; idx += 256) {
            int n = idx / BK, kk = idx % BK;
            Ws[kk][n] = W[(size_t)(n0 + n) * K + k0 + kk];
        }
        __syncthreads();
#pragma unroll
        for (int kk = 0; kk < BK; ++kk) {
            float a[4], w[4];
#pragma unroll
            for (int i = 0; i < 4; ++i) a[i] = As[kk][ty * 4 + i];
#pragma unroll
            for (int j = 0; j < 4; ++j) w[j] = Ws[kk][tx * 4 + j];
#pragma unroll
            for (int i = 0; i < 4; ++i)
#pragma unroll
                for (int j = 0; j < 4; ++j) acc[i][j] += a[i] * w[j];
        }
        __syncthreads();
    }

#pragma unroll
    for (int i = 0; i < 4; ++i) {
        int m = m0 + ty * 4 + i;
#pragma unroll
        for (int j = 0; j < 4; ++j) {
            int n = n0 + tx * 4 + j;
            C[(size_t)m * N + n] = acc[i][j] + bias[n];
        }
    }
}

// Flash-style causal multi-query attention, fp32.
// Q: [S, 1024] (head h = cols h*64..h*64+63), K/V: [S, 64] shared head.
// O: [S, 1024] at (s, h*64+d).
// Grid: (S/32 query tiles, 16 heads), 256 threads. LDS = 50,304 B < 64 KiB.
__global__ void flash_attn_kernel(const float* __restrict__ Q, const float* __restrict__ Km,
                                  const float* __restrict__ Vm, float* __restrict__ O,
                                  int S) {
    const int D = 64, TQ = 32, TK = 64;
    const float NEG = -1e30f;
    const int h = blockIdx.y;
    const int q0 = blockIdx.x * TQ;
    const int tid = threadIdx.x;

    __shared__ float Qs[TQ][D + 1];
    __shared__ float Ks[TK][D + 1];
    __shared__ float Vs[TK][D + 1];
    __shared__ float Ss[TQ][TK + 1];
    __shared__ float mrow[TQ], lrow[TQ], arow[TQ];

    for (int idx = tid; idx < TQ * D; idx += 256) {
        int r = idx / D, d = idx % D;
        Qs[r][d] = Q[(size_t)(q0 + r) * 1024 + h * 64 + d];
    }
    if (tid < TQ) {
        mrow[tid] = NEG;
        lrow[tid] = 0.f;
    }

    float o[8];
#pragma unroll
    for (int i = 0; i < 8; ++i) o[i] = 0.f;

    const int c = tid % 64;     // key col (scores) / output col d (O-update)
    const int rbase = tid / 64; // rows rbase + 4*i
    const float scale = 0.125f; // 1/sqrt(64)

    const int ntiles = (q0 + TQ - 1) / TK + 1; // causal: key tiles 0..last needed
    for (int jt = 0; jt < ntiles; ++jt) {
        const int j0 = jt * TK;
        __syncthreads(); // prior iter's consumers done before overwriting Ks/Vs/Ss
        for (int idx = tid; idx < TK * D; idx += 256) {
            int j = idx / D, d = idx % D;
            Ks[j][d] = Km[(size_t)(j0 + j) * D + d];
            Vs[j][d] = Vm[(size_t)(j0 + j) * D + d];
        }
        __syncthreads();

        // scores: thread handles key column c, rows rbase + 4*i
#pragma unroll
        for (int i = 0; i < 8; ++i) {
            int r = rbase + 4 * i;
            float s = 0.f;
#pragma unroll
            for (int d = 0; d < 64; ++d) s += Qs[r][d] * Ks[c][d];
            s *= scale;
            if (j0 + c > q0 + r) s = NEG; // causal mask (finite, no inf arithmetic)
            Ss[r][c] = s;
        }
        __syncthreads();

        // online softmax row stats (one thread per row)
        if (tid < TQ) {
            int r = tid;
            float m_old = mrow[r];
            float mx = m_old;
            for (int jj = 0; jj < TK; ++jj) mx = fmaxf(mx, Ss[r][jj]);
            float alpha = __expf(m_old - mx); // m_old=-1e30 first tile -> underflows to 0
            float sum = 0.f;
            for (int jj = 0; jj < TK; ++jj) {
                float p = __expf(Ss[r][jj] - mx); // masked: exp(-1e30) -> 0
                Ss[r][jj] = p;
                sum += p;
            }
            mrow[r] = mx;
            lrow[r] = lrow[r] * alpha + sum;
            arow[r] = alpha;
        }
        __syncthreads();

        // O update: o[r][c] = o[r][c]*alpha[r] + sum_j P[r][j] * V[j][c]
#pragma unroll
        for (int i = 0; i < 8; ++i) {
            int r = rbase + 4 * i;
            float acc = 0.f;
#pragma unroll
            for (int jj = 0; jj < 64; ++jj) acc += Ss[r][jj] * Vs[jj][c];
            o[i] = o[i] * arow[r] + acc;
        }
    }
    __syncthreads();

#pragma unroll
    for (int i = 0; i < 8; ++i) {
        int r = rbase + 4 * i;
        O[(size_t)(q0 + r) * 1024 + h * 64 + c] = o[i] / lrow[r];
    }
}

extern "C" void kernel_launch(void* const* d_in, const int* in_sizes, int n_in,
                              void* d_out, int out_size, void* d_ws, size_t ws_size,
                              hipStream_t stream) {
    const int S = 2048, E = 1024, D = 64;

    const float* hs = (const float*)d_in[0];
    // d_in[1] = mask (causal tril) — recomputed in-kernel, not read
    const float* Wq = (const float*)d_in[2];
    const float* bq = (const float*)d_in[3];
    const float* Wk = (const float*)d_in[4];
    const float* bk = (const float*)d_in[5];
    const float* Wv = (const float*)d_in[6];
    const float* bv = (const float*)d_in[7];
    const float* Wo = (const float*)d_in[8];
    const float* bo = (const float*)d_in[9];
    float* out = (float*)d_out;

    float* ws = (float*)d_ws;
    float* q = ws;                   // S*E fp32 (8 MB)
    float* k = q + (size_t)S * E;    // S*D (0.5 MB)
    float* v = k + (size_t)S * D;    // S*D (0.5 MB)
    float* attn = v + (size_t)S * D; // S*E (8 MB)

    dim3 blk(256);
    // projections
    gemm_bt_kernel<<<dim3(E / 64, S / 64), blk, 0, stream>>>(hs, Wq, bq, q, S, E, E);
    gemm_bt_kernel<<<dim3(1, S / 64), blk, 0, stream>>>(hs, Wk, bk, k, S, D, E);
    gemm_bt_kernel<<<dim3(1, S / 64), blk, 0, stream>>>(hs, Wv, bv, v, S, D, E);
    // attention
    flash_attn_kernel<<<dim3(S / 32, 16), blk, 0, stream>>>(q, k, v, attn, S);
    // output projection
    gemm_bt_kernel<<<dim3(E / 64, S / 64), blk, 0, stream>>>(attn, Wo, bo, out, S, E, E);
}

// Round 3
// 241.513 us; speedup vs baseline: 8.5261x; 8.5261x over previous
//
#include <hip/hip_runtime.h>
#include <hip/hip_bf16.h>

typedef __hip_bfloat16 bf16;
typedef __attribute__((ext_vector_type(8))) short short8;   // 8 bf16 = 4 VGPRs
typedef __attribute__((ext_vector_type(4))) float f32x4;    // MFMA C/D frag

__device__ __forceinline__ short8 ld8(const void* p) { return *(const short8*)p; }
__device__ __forceinline__ void st8(void* p, short8 v) { *(short8*)p = v; }

struct bf4 { bf16 a, b, c, d; };

// ---------------------------------------------------------------------------
// fp32 -> bf16 cast, float4 vectorized, grid-stride. n must be %4==0.
__global__ void cast_kernel(const float* __restrict__ s0, bf16* __restrict__ d0, int n0_,
                            const float* __restrict__ s1, bf16* __restrict__ d1, int n1_,
                            const float* __restrict__ s2, bf16* __restrict__ d2, int n2_,
                            const float* __restrict__ s3, bf16* __restrict__ d3, int n3_,
                            const float* __restrict__ s4, bf16* __restrict__ d4, int n4_) {
    const float* srcs[5] = {s0, s1, s2, s3, s4};
    bf16* dsts[5] = {d0, d1, d2, d3, d4};
    int ns[5] = {n0_, n1_, n2_, n3_, n4_};
    int stride = gridDim.x * blockDim.x;
    int t0 = blockIdx.x * blockDim.x + threadIdx.x;
#pragma unroll
    for (int a = 0; a < 5; ++a) {
        const float4* src = (const float4*)srcs[a];
        bf4* dst = (bf4*)dsts[a];
        int n4 = ns[a] >> 2;
        for (int i = t0; i < n4; i += stride) {
            float4 v = src[i];
            bf4 o = {__float2bfloat16(v.x), __float2bfloat16(v.y),
                     __float2bfloat16(v.z), __float2bfloat16(v.w)};
            dst[i] = o;
        }
    }
}

// ---------------------------------------------------------------------------
// C[M,N] = A[M,K](bf16) @ W[N,K](bf16)^T + bias(fp32).
// 64x64 tile, BK=32, 256 threads = 4 waves, each wave a 32x32 quadrant
// (2x2 frags of 16x16x32 MFMA). TR: store C^T[N,M] instead.
template <typename CT, bool TR>
__global__ void gemm_bt_mfma(const bf16* __restrict__ A, const bf16* __restrict__ W,
                             const float* __restrict__ bias, CT* __restrict__ C,
                             int M, int N, int K) {
    __shared__ bf16 As[64][40]; // +8 pad: row stride 80B -> 2-way (free) on b128 reads
    __shared__ bf16 Bs[64][40];
    const int tid = threadIdx.x;
    const int wave = tid >> 6, lane = tid & 63;
    const int l16 = lane & 15, quad = lane >> 4;
    const int wm = wave & 1, wn = wave >> 1;
    const int m0 = blockIdx.y * 64, n0 = blockIdx.x * 64;
    const int sr = tid >> 2, sc = (tid & 3) * 8; // staging: row, col-chunk (64x32 = 256x8)

    f32x4 acc[2][2] = {};
    const f32x4 z = {0.f, 0.f, 0.f, 0.f};
    acc[0][0] = z; acc[0][1] = z; acc[1][0] = z; acc[1][1] = z;

    for (int k0 = 0; k0 < K; k0 += 32) {
        st8(&As[sr][sc], ld8(A + (size_t)(m0 + sr) * K + k0 + sc));
        st8(&Bs[sr][sc], ld8(W + (size_t)(n0 + sr) * K + k0 + sc));
        __syncthreads();
        short8 af[2], bf[2];
#pragma unroll
        for (int mi = 0; mi < 2; ++mi) af[mi] = ld8(&As[wm * 32 + mi * 16 + l16][quad * 8]);
#pragma unroll
        for (int ni = 0; ni < 2; ++ni) bf[ni] = ld8(&Bs[wn * 32 + ni * 16 + l16][quad * 8]);
#pragma unroll
        for (int mi = 0; mi < 2; ++mi)
#pragma unroll
            for (int ni = 0; ni < 2; ++ni)
                acc[mi][ni] = __builtin_amdgcn_mfma_f32_16x16x32_bf16(af[mi], bf[ni], acc[mi][ni], 0, 0, 0);
        __syncthreads();
    }

    // epilogue: C/D layout col=lane&15, row=quad*4+reg  [m89]
#pragma unroll
    for (int mi = 0; mi < 2; ++mi)
#pragma unroll
        for (int ni = 0; ni < 2; ++ni)
#pragma unroll
            for (int r = 0; r < 4; ++r) {
                int row = m0 + wm * 32 + mi * 16 + quad * 4 + r;
                int col = n0 + wn * 32 + ni * 16 + l16;
                float v = acc[mi][ni][r] + bias[col];
                size_t idx = TR ? ((size_t)col * M + row) : ((size_t)row * N + col);
                if constexpr (sizeof(CT) == 2) C[idx] = __float2bfloat16(v);
                else C[idx] = v;
            }
}

// ---------------------------------------------------------------------------
// Flash causal MQA, bf16 MFMA. Q[S,1024] bf16, K[S,64] bf16, VT[64,S] bf16.
// attn out [S,1024] bf16 at (s, h*64+d). Grid (S/64, 16 heads), 256 thr = 4 waves,
// wave handles 16 query rows. LDS 27,648 B.
__global__ void flash_mfma_kernel(const bf16* __restrict__ Q, const bf16* __restrict__ Kg,
                                  const bf16* __restrict__ VT, bf16* __restrict__ Og,
                                  int S) {
    __shared__ bf16 Ks[64][72]; // [key][d], +8 pad
    __shared__ bf16 Vt[64][72]; // [d][key], +8 pad
    __shared__ bf16 Ps[4][16][72]; // per-wave P tile [qrow][key]

    const int h = blockIdx.y;
    const int q0 = blockIdx.x * 64;
    const int tid = threadIdx.x;
    const int wave = tid >> 6, lane = tid & 63;
    const int l16 = lane & 15, quad = lane >> 4;
    const int qrow = q0 + wave * 16; // wave's 16-query strip base
    const float scale = 0.125f;     // 1/sqrt(64)

    // Q A-frags (k-dim = d, 2 chunks of 32), direct from global [m120 A-layout]
    short8 qf[2];
#pragma unroll
    for (int kc = 0; kc < 2; ++kc)
        qf[kc] = ld8(Q + (size_t)(qrow + l16) * 1024 + h * 64 + kc * 32 + quad * 8);

    f32x4 of[4];
    const f32x4 z = {0.f, 0.f, 0.f, 0.f};
#pragma unroll
    for (int dt = 0; dt < 4; ++dt) of[dt] = z;
    float m_run[4], l_run[4];
#pragma unroll
    for (int r = 0; r < 4; ++r) { m_run[r] = -1e30f; l_run[r] = 0.f; }

    const int ntiles = blockIdx.x + 1; // causal
    for (int jt = 0; jt < ntiles; ++jt) {
        const int j0 = jt * 64;
        __syncthreads(); // prior tile's consumers done
        // stage K tile and V^T tile: 4096 elems each, 2 x short8 per thread
#pragma unroll
        for (int i = 0; i < 2; ++i) {
            int e = tid + i * 256;
            int r = e >> 3, c8 = (e & 7) * 8;
            st8(&Ks[r][c8], ld8(Kg + (size_t)(j0 + r) * 64 + c8));
            st8(&Vt[r][c8], ld8(VT + (size_t)r * S + j0 + c8));
        }
        __syncthreads();

        // S = Q K^T : 4 key n-tiles x 2 k-chunks
        f32x4 s[4];
#pragma unroll
        for (int nt = 0; nt < 4; ++nt) {
            s[nt] = __builtin_amdgcn_mfma_f32_16x16x32_bf16(
                qf[0], ld8(&Ks[nt * 16 + l16][quad * 8]), z, 0, 0, 0);
            s[nt] = __builtin_amdgcn_mfma_f32_16x16x32_bf16(
                qf[1], ld8(&Ks[nt * 16 + l16][32 + quad * 8]), s[nt], 0, 0, 0);
        }
        // scale + causal mask (C layout: col = j0+nt*16+l16, row = qrow+quad*4+r)
        bool need_mask = (j0 + 63 > qrow);
#pragma unroll
        for (int nt = 0; nt < 4; ++nt)
#pragma unroll
            for (int r = 0; r < 4; ++r) {
                float v = s[nt][r] * scale;
                if (need_mask && (j0 + nt * 16 + l16 > qrow + quad * 4 + r)) v = -1e30f;
                s[nt][r] = v;
            }

        // online softmax, per-row stats via shfl over the 16-lane quad-group
        float tm[4];
#pragma unroll
        for (int r = 0; r < 4; ++r)
            tm[r] = fmaxf(fmaxf(s[0][r], s[1][r]), fmaxf(s[2][r], s[3][r]));
#pragma unroll
        for (int msk = 1; msk < 16; msk <<= 1)
#pragma unroll
            for (int r = 0; r < 4; ++r) tm[r] = fmaxf(tm[r], __shfl_xor(tm[r], msk));
        float alpha[4], ts[4];
#pragma unroll
        for (int r = 0; r < 4; ++r) {
            float mn = fmaxf(m_run[r], tm[r]);
            alpha[r] = __expf(m_run[r] - mn);
            m_run[r] = mn;
            ts[r] = 0.f;
        }
#pragma unroll
        for (int nt = 0; nt < 4; ++nt)
#pragma unroll
            for (int r = 0; r < 4; ++r) {
                float p = __expf(s[nt][r] - m_run[r]);
                s[nt][r] = p;
                ts[r] += p;
            }
#pragma unroll
        for (int msk = 1; msk < 16; msk <<= 1)
#pragma unroll
            for (int r = 0; r < 4; ++r) ts[r] += __shfl_xor(ts[r], msk);
#pragma unroll
        for (int r = 0; r < 4; ++r) l_run[r] = l_run[r] * alpha[r] + ts[r];

        // P -> LDS (C layout -> A layout round-trip) [m120]
#pragma unroll
        for (int nt = 0; nt < 4; ++nt)
#pragma unroll
            for (int r = 0; r < 4; ++r)
                Ps[wave][quad * 4 + r][nt * 16 + l16] = __float2bfloat16(s[nt][r]);
        __syncthreads();

        // O = O*alpha + P V
#pragma unroll
        for (int dt = 0; dt < 4; ++dt)
#pragma unroll
            for (int r = 0; r < 4; ++r) of[dt][r] *= alpha[r];
        short8 pf[2];
#pragma unroll
        for (int kc = 0; kc < 2; ++kc) pf[kc] = ld8(&Ps[wave][l16][kc * 32 + quad * 8]);
#pragma unroll
        for (int dt = 0; dt < 4; ++dt) {
            of[dt] = __builtin_amdgcn_mfma_f32_16x16x32_bf16(
                pf[0], ld8(&Vt[dt * 16 + l16][quad * 8]), of[dt], 0, 0, 0);
            of[dt] = __builtin_amdgcn_mfma_f32_16x16x32_bf16(
                pf[1], ld8(&Vt[dt * 16 + l16][32 + quad * 8]), of[dt], 0, 0, 0);
        }
    }

    // epilogue: O /= l, store bf16
#pragma unroll
    for (int dt = 0; dt < 4; ++dt)
#pragma unroll
        for (int r = 0; r < 4; ++r) {
            float v = of[dt][r] / l_run[r];
            Og[(size_t)(qrow + quad * 4 + r) * 1024 + h * 64 + dt * 16 + l16] =
                __float2bfloat16(v);
        }
}

// ---------------------------------------------------------------------------
extern "C" void kernel_launch(void* const* d_in, const int* in_sizes, int n_in,
                              void* d_out, int out_size, void* d_ws, size_t ws_size,
                              hipStream_t stream) {
    const int S = 2048, E = 1024, D = 64;

    const float* hs = (const float*)d_in[0];
    // d_in[1] = mask — causality recomputed analytically
    const float* Wq = (const float*)d_in[2];
    const float* bq = (const float*)d_in[3];
    const float* Wk = (const float*)d_in[4];
    const float* bk = (const float*)d_in[5];
    const float* Wv = (const float*)d_in[6];
    const float* bv = (const float*)d_in[7];
    const float* Wo = (const float*)d_in[8];
    const float* bo = (const float*)d_in[9];
    float* out = (float*)d_out;

    // workspace layout (bf16 elements unless noted)
    bf16* ws = (bf16*)d_ws;
    bf16* hsb = ws;                       // S*E
    bf16* wqb = hsb + (size_t)S * E;      // E*E
    bf16* wkb = wqb + (size_t)E * E;      // D*E
    bf16* wvb = wkb + (size_t)D * E;      // D*E
    bf16* wob = wvb + (size_t)D * E;      // E*E
    bf16* q = wob + (size_t)E * E;        // S*E
    bf16* kbuf = q + (size_t)S * E;       // S*D
    bf16* vt = kbuf + (size_t)S * D;      // D*S (transposed)
    bf16* attn = vt + (size_t)S * D;      // S*E

    dim3 blk(256);
    cast_kernel<<<512, blk, 0, stream>>>(hs, hsb, S * E,
                                         Wq, wqb, E * E,
                                         Wk, wkb, D * E,
                                         Wv, wvb, D * E,
                                         Wo, wob, E * E);
    // projections (MFMA)
    gemm_bt_mfma<bf16, false><<<dim3(E / 64, S / 64), blk, 0, stream>>>(hsb, wqb, bq, q, S, E, E);
    gemm_bt_mfma<bf16, false><<<dim3(1, S / 64), blk, 0, stream>>>(hsb, wkb, bk, kbuf, S, D, E);
    gemm_bt_mfma<bf16, true><<<dim3(1, S / 64), blk, 0, stream>>>(hsb, wvb, bv, vt, S, D, E);
    // attention (MFMA flash)
    flash_mfma_kernel<<<dim3(S / 64, 16), blk, 0, stream>>>(q, kbuf, vt, attn, S);
    // output projection (fp32 out)
    gemm_bt_mfma<float, false><<<dim3(E / 64, S / 64), blk, 0, stream>>>(attn, wob, bo, out, S, E, E);
}

// Round 4
// 220.275 us; speedup vs baseline: 9.3481x; 1.0964x over previous
//
#include <hip/hip_runtime.h>
#include <hip/hip_bf16.h>

typedef __hip_bfloat16 bf16;
typedef __attribute__((ext_vector_type(8))) short short8;   // 8 bf16 = 4 VGPRs
typedef __attribute__((ext_vector_type(4))) float f32x4;    // MFMA C/D frag

__device__ __forceinline__ short8 ld8(const void* p) { return *(const short8*)p; }
__device__ __forceinline__ void st8(void* p, short8 v) { *(short8*)p = v; }

// async global->LDS, 16B per lane: LDS dest = (wave-uniform) lds + lane*16
__device__ __forceinline__ void async_cp16(bf16* lds, const bf16* g) {
    __builtin_amdgcn_global_load_lds(
        (const __attribute__((address_space(1))) unsigned int*)g,
        (__attribute__((address_space(3))) unsigned int*)lds, 16, 0, 0);
}

struct bf4 { bf16 a, b, c, d; };

// ---------------------------------------------------------------------------
__global__ void cast_kernel(const float* __restrict__ s0, bf16* __restrict__ d0, int n0_,
                            const float* __restrict__ s1, bf16* __restrict__ d1, int n1_,
                            const float* __restrict__ s2, bf16* __restrict__ d2, int n2_,
                            const float* __restrict__ s3, bf16* __restrict__ d3, int n3_,
                            const float* __restrict__ s4, bf16* __restrict__ d4, int n4_) {
    const float* srcs[5] = {s0, s1, s2, s3, s4};
    bf16* dsts[5] = {d0, d1, d2, d3, d4};
    int ns[5] = {n0_, n1_, n2_, n3_, n4_};
    int stride = gridDim.x * blockDim.x;
    int t0 = blockIdx.x * blockDim.x + threadIdx.x;
#pragma unroll
    for (int a = 0; a < 5; ++a) {
        const float4* src = (const float4*)srcs[a];
        bf4* dst = (bf4*)dsts[a];
        int n4 = ns[a] >> 2;
        for (int i = t0; i < n4; i += stride) {
            float4 v = src[i];
            bf4 o = {__float2bfloat16(v.x), __float2bfloat16(v.y),
                     __float2bfloat16(v.z), __float2bfloat16(v.w)};
            dst[i] = o;
        }
    }
}

// ---------------------------------------------------------------------------
// C[M,N] = A[M,K](bf16) @ W[N,K](bf16)^T + bias(fp32).
// Tile 128x64, BK=64, 256 thr = 4 waves; wave owns a 32x64 strip (2x4 frags).
// Staging via global_load_lds(16B) into UNPADDED LDS with XOR-swizzled 8-elem
// chunks: slot(r, s) holds global chunk c = s ^ (r&7)  -> conflict-free
// ds_read_b128 frag reads (each 8-lane phase covers all 8 bank groups).
// tr: store C^T[N,M] instead (for V^T).
template <typename CT>
__global__ void gemm_bt_mfma(const bf16* __restrict__ A, const bf16* __restrict__ W,
                             const float* __restrict__ bias, CT* __restrict__ C,
                             int M, int N, int K, int tr) {
    __shared__ __align__(16) bf16 As[128][64]; // 16 KB
    __shared__ __align__(16) bf16 Bs[64][64];  // 8 KB
    const int tid = threadIdx.x;
    const int wave = tid >> 6, lane = tid & 63;
    const int l16 = lane & 15, quad = lane >> 4;
    const int m0 = blockIdx.y * 128, n0 = blockIdx.x * 64;
    const int lr = lane >> 3, lsw = (lane & 7) ^ (lr & 7); // lane's slot row-offset, src chunk

    f32x4 acc[2][4];
    const f32x4 z = {0.f, 0.f, 0.f, 0.f};
#pragma unroll
    for (int mi = 0; mi < 2; ++mi)
#pragma unroll
        for (int ni = 0; ni < 4; ++ni) acc[mi][ni] = z;

    for (int k0 = 0; k0 < K; k0 += 64) {
        // A: 16 insts of 8 rows; wave w issues t = 4w..4w+3
#pragma unroll
        for (int u = 0; u < 4; ++u) {
            int t = wave * 4 + u;
            int r = t * 8 + lr;
            async_cp16(&As[t * 8][0], A + (size_t)(m0 + r) * K + k0 + lsw * 8);
        }
        // B: 8 insts; wave w issues t = 2w..2w+1
#pragma unroll
        for (int u = 0; u < 2; ++u) {
            int t = wave * 2 + u;
            int r = t * 8 + lr;
            async_cp16(&Bs[t * 8][0], W + (size_t)(n0 + r) * K + k0 + lsw * 8);
        }
        __syncthreads(); // drains vmcnt before barrier

        short8 af[2][2], bfr[2][4];
#pragma unroll
        for (int mi = 0; mi < 2; ++mi)
#pragma unroll
            for (int kc = 0; kc < 2; ++kc) {
                int R = wave * 32 + mi * 16 + l16;
                int g = kc * 4 + quad;
                af[mi][kc] = ld8(&As[R][(g ^ (R & 7)) * 8]);
            }
#pragma unroll
        for (int ni = 0; ni < 4; ++ni)
#pragma unroll
            for (int kc = 0; kc < 2; ++kc) {
                int r = ni * 16 + l16;
                int g = kc * 4 + quad;
                bfr[kc][ni] = ld8(&Bs[r][(g ^ (r & 7)) * 8]);
            }
#pragma unroll
        for (int kc = 0; kc < 2; ++kc)
#pragma unroll
            for (int mi = 0; mi < 2; ++mi)
#pragma unroll
                for (int ni = 0; ni < 4; ++ni)
                    acc[mi][ni] = __builtin_amdgcn_mfma_f32_16x16x32_bf16(
                        af[mi][kc], bfr[kc][ni], acc[mi][ni], 0, 0, 0);
        __syncthreads();
    }

    // epilogue: C/D layout col=lane&15, row=quad*4+reg [m89]
#pragma unroll
    for (int mi = 0; mi < 2; ++mi)
#pragma unroll
        for (int ni = 0; ni < 4; ++ni)
#pragma unroll
            for (int r = 0; r < 4; ++r) {
                int row = m0 + wave * 32 + mi * 16 + quad * 4 + r;
                int col = n0 + ni * 16 + l16;
                float v = acc[mi][ni][r] + bias[col];
                size_t idx = tr ? ((size_t)col * M + row) : ((size_t)row * N + col);
                if constexpr (sizeof(CT) == 2) C[idx] = __float2bfloat16(v);
                else C[idx] = v;
            }
}

// ---------------------------------------------------------------------------
// Flash causal MQA, phase A (k-split). Chunk = 16 k-tiles = 1024 keys.
// Grid (64, 16): x -> (qtile i = x&31, chunk c = x>>5); active iff c*16 <= i.
// Writes UNNORMALIZED partial O (64x64 f32) + per-row m,l to workspace.
__global__ void flash_mfma_kernel(const bf16* __restrict__ Q, const bf16* __restrict__ Kg,
                                  const bf16* __restrict__ VT,
                                  float* __restrict__ Opart, float* __restrict__ MLpart,
                                  int S) {
    const int i = blockIdx.x & 31;
    const int c = blockIdx.x >> 5;
    if (c * 16 > i) return; // chunk not needed for this q-tile

    __shared__ bf16 Ks[64][72];
    __shared__ bf16 Vt[64][72];
    __shared__ bf16 Ps[4][16][72];

    const int h = blockIdx.y;
    const int q0 = i * 64;
    const int tid = threadIdx.x;
    const int wave = tid >> 6, lane = tid & 63;
    const int l16 = lane & 15, quad = lane >> 4;
    const int qrow = q0 + wave * 16;
    const float scale = 0.125f;

    short8 qf[2];
#pragma unroll
    for (int kc = 0; kc < 2; ++kc)
        qf[kc] = ld8(Q + (size_t)(qrow + l16) * 1024 + h * 64 + kc * 32 + quad * 8);

    f32x4 of[4];
    const f32x4 z = {0.f, 0.f, 0.f, 0.f};
#pragma unroll
    for (int dt = 0; dt < 4; ++dt) of[dt] = z;
    float m_run[4], l_run[4];
#pragma unroll
    for (int r = 0; r < 4; ++r) { m_run[r] = -1e30f; l_run[r] = 0.f; }

    const int t0 = c * 16;
    const int tend = min(c * 16 + 16, i + 1);
    for (int jt = t0; jt < tend; ++jt) {
        const int j0 = jt * 64;
        __syncthreads();
#pragma unroll
        for (int u = 0; u < 2; ++u) {
            int e = tid + u * 256;
            int r = e >> 3, c8 = (e & 7) * 8;
            st8(&Ks[r][c8], ld8(Kg + (size_t)(j0 + r) * 64 + c8));
            st8(&Vt[r][c8], ld8(VT + (size_t)r * S + j0 + c8));
        }
        __syncthreads();

        f32x4 s[4];
#pragma unroll
        for (int nt = 0; nt < 4; ++nt) {
            s[nt] = __builtin_amdgcn_mfma_f32_16x16x32_bf16(
                qf[0], ld8(&Ks[nt * 16 + l16][quad * 8]), z, 0, 0, 0);
            s[nt] = __builtin_amdgcn_mfma_f32_16x16x32_bf16(
                qf[1], ld8(&Ks[nt * 16 + l16][32 + quad * 8]), s[nt], 0, 0, 0);
        }
        bool need_mask = (j0 + 63 > qrow);
#pragma unroll
        for (int nt = 0; nt < 4; ++nt)
#pragma unroll
            for (int r = 0; r < 4; ++r) {
                float v = s[nt][r] * scale;
                if (need_mask && (j0 + nt * 16 + l16 > qrow + quad * 4 + r)) v = -1e30f;
                s[nt][r] = v;
            }

        float tm[4];
#pragma unroll
        for (int r = 0; r < 4; ++r)
            tm[r] = fmaxf(fmaxf(s[0][r], s[1][r]), fmaxf(s[2][r], s[3][r]));
#pragma unroll
        for (int msk = 1; msk < 16; msk <<= 1)
#pragma unroll
            for (int r = 0; r < 4; ++r) tm[r] = fmaxf(tm[r], __shfl_xor(tm[r], msk));
        float alpha[4], ts[4];
#pragma unroll
        for (int r = 0; r < 4; ++r) {
            float mn = fmaxf(m_run[r], tm[r]);
            alpha[r] = __expf(m_run[r] - mn);
            m_run[r] = mn;
            ts[r] = 0.f;
        }
#pragma unroll
        for (int nt = 0; nt < 4; ++nt)
#pragma unroll
            for (int r = 0; r < 4; ++r) {
                float p = __expf(s[nt][r] - m_run[r]);
                s[nt][r] = p;
                ts[r] += p;
            }
#pragma unroll
        for (int msk = 1; msk < 16; msk <<= 1)
#pragma unroll
            for (int r = 0; r < 4; ++r) ts[r] += __shfl_xor(ts[r], msk);
#pragma unroll
        for (int r = 0; r < 4; ++r) l_run[r] = l_run[r] * alpha[r] + ts[r];

#pragma unroll
        for (int nt = 0; nt < 4; ++nt)
#pragma unroll
            for (int r = 0; r < 4; ++r)
                Ps[wave][quad * 4 + r][nt * 16 + l16] = __float2bfloat16(s[nt][r]);
        __syncthreads();

#pragma unroll
        for (int dt = 0; dt < 4; ++dt)
#pragma unroll
            for (int r = 0; r < 4; ++r) of[dt][r] *= alpha[r];
        short8 pf[2];
#pragma unroll
        for (int kc = 0; kc < 2; ++kc) pf[kc] = ld8(&Ps[wave][l16][kc * 32 + quad * 8]);
#pragma unroll
        for (int dt = 0; dt < 4; ++dt) {
            of[dt] = __builtin_amdgcn_mfma_f32_16x16x32_bf16(
                pf[0], ld8(&Vt[dt * 16 + l16][quad * 8]), of[dt], 0, 0, 0);
            of[dt] = __builtin_amdgcn_mfma_f32_16x16x32_bf16(
                pf[1], ld8(&Vt[dt * 16 + l16][32 + quad * 8]), of[dt], 0, 0, 0);
        }
    }

    // write partials: slot = (i*2 + c)*16 + h
    const int slot = (i * 2 + c) * 16 + h;
    float* Op = Opart + (size_t)slot * 4096;
#pragma unroll
    for (int dt = 0; dt < 4; ++dt)
#pragma unroll
        for (int r = 0; r < 4; ++r) {
            int row = wave * 16 + quad * 4 + r;
            Op[row * 64 + dt * 16 + l16] = of[dt][r];
        }
    if (l16 == 0) { // m/l uniform across the 16-lane quad group after shfl reduce
        float* ML = MLpart + (size_t)slot * 128;
#pragma unroll
        for (int r = 0; r < 4; ++r) {
            int row = wave * 16 + quad * 4 + r;
            ML[row] = m_run[r];
            ML[64 + row] = l_run[r];
        }
    }
}

// ---------------------------------------------------------------------------
// Merge <=2 partials per (q-tile, head) -> attn bf16 [S, 1024] at (s, h*64+d).
__global__ void flash_merge_kernel(const float* __restrict__ Opart,
                                   const float* __restrict__ MLpart,
                                   bf16* __restrict__ attn) {
    const int i = blockIdx.x, h = blockIdx.y;
    const int nch = (i >> 4) + 1; // 1 or 2 chunks
    const int tid = threadIdx.x;
    const int row = tid >> 2, cg = (tid & 3) * 16;

    float m[2], l[2];
    for (int cc = 0; cc < nch; ++cc) {
        int slot = (i * 2 + cc) * 16 + h;
        m[cc] = MLpart[(size_t)slot * 128 + row];
        l[cc] = MLpart[(size_t)slot * 128 + 64 + row];
    }
    float M = m[0];
    if (nch == 2) M = fmaxf(M, m[1]);
    float L = 0.f, w[2];
    for (int cc = 0; cc < nch; ++cc) {
        w[cc] = __expf(m[cc] - M);
        L += l[cc] * w[cc];
    }
    float inv = 1.f / L;

    float o[16];
#pragma unroll
    for (int j = 0; j < 16; ++j) o[j] = 0.f;
    for (int cc = 0; cc < nch; ++cc) {
        const float* Op = Opart + (size_t)((i * 2 + cc) * 16 + h) * 4096 + row * 64 + cg;
#pragma unroll
        for (int j = 0; j < 16; ++j) o[j] += Op[j] * w[cc];
    }
    bf16* dst = attn + (size_t)(i * 64 + row) * 1024 + h * 64 + cg;
#pragma unroll
    for (int j = 0; j < 16; ++j) dst[j] = __float2bfloat16(o[j] * inv);
}

// ---------------------------------------------------------------------------
extern "C" void kernel_launch(void* const* d_in, const int* in_sizes, int n_in,
                              void* d_out, int out_size, void* d_ws, size_t ws_size,
                              hipStream_t stream) {
    const int S = 2048, E = 1024, D = 64;

    const float* hs = (const float*)d_in[0];
    const float* Wq = (const float*)d_in[2];
    const float* bq = (const float*)d_in[3];
    const float* Wk = (const float*)d_in[4];
    const float* bk = (const float*)d_in[5];
    const float* Wv = (const float*)d_in[6];
    const float* bv = (const float*)d_in[7];
    const float* Wo = (const float*)d_in[8];
    const float* bo = (const float*)d_in[9];
    float* out = (float*)d_out;

    bf16* ws = (bf16*)d_ws;
    bf16* hsb = ws;                       // S*E
    bf16* wqb = hsb + (size_t)S * E;      // E*E
    bf16* wkb = wqb + (size_t)E * E;      // D*E
    bf16* wvb = wkb + (size_t)D * E;      // D*E
    bf16* wob = wvb + (size_t)D * E;      // E*E
    bf16* q = wob + (size_t)E * E;        // S*E
    bf16* kbuf = q + (size_t)S * E;       // S*D
    bf16* vt = kbuf + (size_t)S * D;      // D*S (transposed)
    bf16* attn = vt + (size_t)S * D;      // S*E
    float* Opart = (float*)(attn + (size_t)S * E); // 1024 slots * 4096 f32 (16.8 MB)
    float* MLpart = Opart + (size_t)1024 * 4096;   // 1024 * 128 f32 (0.5 MB)

    dim3 blk(256);
    cast_kernel<<<512, blk, 0, stream>>>(hs, hsb, S * E,
                                         Wq, wqb, E * E,
                                         Wk, wkb, D * E,
                                         Wv, wvb, D * E,
                                         Wo, wob, E * E);
    // projections (128x64-tile MFMA + global_load_lds)
    gemm_bt_mfma<bf16><<<dim3(E / 64, S / 128), blk, 0, stream>>>(hsb, wqb, bq, q, S, E, E, 0);
    gemm_bt_mfma<bf16><<<dim3(1, S / 128), blk, 0, stream>>>(hsb, wkb, bk, kbuf, S, D, E, 0);
    gemm_bt_mfma<bf16><<<dim3(1, S / 128), blk, 0, stream>>>(hsb, wvb, bv, vt, S, D, E, 1);
    // attention: k-split phase A + merge
    flash_mfma_kernel<<<dim3(64, 16), blk, 0, stream>>>(q, kbuf, vt, Opart, MLpart, S);
    flash_merge_kernel<<<dim3(32, 16), blk, 0, stream>>>(Opart, MLpart, attn);
    // output projection (fp32 out)
    gemm_bt_mfma<float><<<dim3(E / 64, S / 128), blk, 0, stream>>>(attn, wob, bo, out, S, E, E, 0);
}

// Round 5
// 209.254 us; speedup vs baseline: 9.8405x; 1.0527x over previous
//
#include <hip/hip_runtime.h>
#include <hip/hip_bf16.h>

typedef __hip_bfloat16 bf16;
typedef __attribute__((ext_vector_type(8))) short short8;   // 8 bf16 = 4 VGPRs
typedef __attribute__((ext_vector_type(4))) float f32x4;    // MFMA C/D frag

__device__ __forceinline__ short8 ld8(const void* p) { return *(const short8*)p; }
__device__ __forceinline__ void st8(void* p, short8 v) { *(short8*)p = v; }

// async global->LDS, 16B per lane: LDS dest = (wave-uniform) base + lane*16
__device__ __forceinline__ void async_cp16(bf16* lds, const bf16* g) {
    __builtin_amdgcn_global_load_lds(
        (const __attribute__((address_space(1))) unsigned int*)g,
        (__attribute__((address_space(3))) unsigned int*)lds, 16, 0, 0);
}

struct bf4 { bf16 a, b, c, d; };

// ---------------------------------------------------------------------------
__global__ void cast_kernel(const float* __restrict__ s0, bf16* __restrict__ d0, int n0_,
                            const float* __restrict__ s1, bf16* __restrict__ d1, int n1_,
                            const float* __restrict__ s2, bf16* __restrict__ d2, int n2_,
                            const float* __restrict__ s3, bf16* __restrict__ d3, int n3_,
                            const float* __restrict__ s4, bf16* __restrict__ d4, int n4_) {
    const float* srcs[5] = {s0, s1, s2, s3, s4};
    bf16* dsts[5] = {d0, d1, d2, d3, d4};
    int ns[5] = {n0_, n1_, n2_, n3_, n4_};
    int stride = gridDim.x * blockDim.x;
    int t0 = blockIdx.x * blockDim.x + threadIdx.x;
#pragma unroll
    for (int a = 0; a < 5; ++a) {
        const float4* src = (const float4*)srcs[a];
        bf4* dst = (bf4*)dsts[a];
        int n4 = ns[a] >> 2;
        for (int i = t0; i < n4; i += stride) {
            float4 v = src[i];
            bf4 o = {__float2bfloat16(v.x), __float2bfloat16(v.y),
                     __float2bfloat16(v.z), __float2bfloat16(v.w)};
            dst[i] = o;
        }
    }
}

// ---------------------------------------------------------------------------
// C[M,N] = (A[M,K](bf16) @ W[N,K](bf16)^T + bias) * bscale.
// Tile 128x64, BK=64, 256 thr = 4 waves; wave owns a 32x64 strip (2x4 frags).
// global_load_lds(16B) into unpadded XOR-swizzled LDS (slot s holds chunk
// s^(r&7)). tr: store C^T[N,M].
template <typename CT>
__global__ void gemm_bt_mfma(const bf16* __restrict__ A, const bf16* __restrict__ W,
                             const float* __restrict__ bias, CT* __restrict__ C,
                             int M, int N, int K, int tr, float bscale) {
    __shared__ __align__(16) bf16 As[128][64]; // 16 KB
    __shared__ __align__(16) bf16 Bs[64][64];  // 8 KB
    const int tid = threadIdx.x;
    const int wave = tid >> 6, lane = tid & 63;
    const int l16 = lane & 15, quad = lane >> 4;
    const int m0 = blockIdx.y * 128, n0 = blockIdx.x * 64;
    const int lr = lane >> 3, lsw = (lane & 7) ^ (lr & 7);

    f32x4 acc[2][4];
    const f32x4 z = {0.f, 0.f, 0.f, 0.f};
#pragma unroll
    for (int mi = 0; mi < 2; ++mi)
#pragma unroll
        for (int ni = 0; ni < 4; ++ni) acc[mi][ni] = z;

    for (int k0 = 0; k0 < K; k0 += 64) {
#pragma unroll
        for (int u = 0; u < 4; ++u) {
            int t = wave * 4 + u;
            async_cp16(&As[t * 8][0], A + (size_t)(m0 + t * 8 + lr) * K + k0 + lsw * 8);
        }
#pragma unroll
        for (int u = 0; u < 2; ++u) {
            int t = wave * 2 + u;
            async_cp16(&Bs[t * 8][0], W + (size_t)(n0 + t * 8 + lr) * K + k0 + lsw * 8);
        }
        __syncthreads(); // drains vmcnt before barrier

        short8 af[2][2], bfr[2][4];
#pragma unroll
        for (int mi = 0; mi < 2; ++mi)
#pragma unroll
            for (int kc = 0; kc < 2; ++kc) {
                int R = wave * 32 + mi * 16 + l16;
                int g = kc * 4 + quad;
                af[mi][kc] = ld8(&As[R][(g ^ (R & 7)) * 8]);
            }
#pragma unroll
        for (int ni = 0; ni < 4; ++ni)
#pragma unroll
            for (int kc = 0; kc < 2; ++kc) {
                int r = ni * 16 + l16;
                int g = kc * 4 + quad;
                bfr[kc][ni] = ld8(&Bs[r][(g ^ (r & 7)) * 8]);
            }
#pragma unroll
        for (int kc = 0; kc < 2; ++kc)
#pragma unroll
            for (int mi = 0; mi < 2; ++mi)
#pragma unroll
                for (int ni = 0; ni < 4; ++ni)
                    acc[mi][ni] = __builtin_amdgcn_mfma_f32_16x16x32_bf16(
                        af[mi][kc], bfr[kc][ni], acc[mi][ni], 0, 0, 0);
        __syncthreads();
    }

#pragma unroll
    for (int mi = 0; mi < 2; ++mi)
#pragma unroll
        for (int ni = 0; ni < 4; ++ni)
#pragma unroll
            for (int r = 0; r < 4; ++r) {
                int row = m0 + wave * 32 + mi * 16 + quad * 4 + r;
                int col = n0 + ni * 16 + l16;
                float v = (acc[mi][ni][r] + bias[col]) * bscale;
                size_t idx = tr ? ((size_t)col * M + row) : ((size_t)row * N + col);
                if constexpr (sizeof(CT) == 2) C[idx] = __float2bfloat16(v);
                else C[idx] = v;
            }
}

// ---------------------------------------------------------------------------
// Flash causal MQA phase A. Chunk = 8 k-tiles (512 keys); 80 equal-ish slots
// per head: s<32 -> (c=0,i=s); <56 -> (c=1,i=s-24); <72 -> (c=2,i=s-40);
// else (c=3,i=s-48). Every block active, <=8 iters. Q is pre-scaled by 1/8.
// Writes unnormalized partial O (64x64 f32) + per-row m,l at slot (s,h).
__global__ void flash_mfma_kernel(const bf16* __restrict__ Q, const bf16* __restrict__ Kg,
                                  const bf16* __restrict__ VT,
                                  float* __restrict__ Opart, float* __restrict__ MLpart,
                                  int S) {
    const int s = blockIdx.x;
    int i, c;
    if (s < 32)      { c = 0; i = s; }
    else if (s < 56) { c = 1; i = s - 24; }
    else if (s < 72) { c = 2; i = s - 40; }
    else             { c = 3; i = s - 48; }

    __shared__ __align__(16) bf16 Ks[64][64]; // XOR-swizzled, 8 KB
    __shared__ __align__(16) bf16 Vt[64][64]; // XOR-swizzled, 8 KB
    __shared__ bf16 Ps[4][16][68];            // stride 68: quad write banks disjoint

    const int h = blockIdx.y;
    const int q0 = i * 64;
    const int tid = threadIdx.x;
    const int wave = tid >> 6, lane = tid & 63;
    const int l16 = lane & 15, quad = lane >> 4;
    const int lr = lane >> 3, lsw = (lane & 7) ^ (lr & 7);
    const int qrow = q0 + wave * 16;

    short8 qf[2];
#pragma unroll
    for (int kc = 0; kc < 2; ++kc)
        qf[kc] = ld8(Q + (size_t)(qrow + l16) * 1024 + h * 64 + kc * 32 + quad * 8);

    f32x4 of[4];
    const f32x4 z = {0.f, 0.f, 0.f, 0.f};
#pragma unroll
    for (int dt = 0; dt < 4; ++dt) of[dt] = z;
    float m_run[4], l_run[4];
#pragma unroll
    for (int r = 0; r < 4; ++r) { m_run[r] = -1e30f; l_run[r] = 0.f; }

    const int jt0 = c * 8;
    const int jt1 = min(c * 8 + 8, i + 1);
    for (int jt = jt0; jt < jt1; ++jt) {
        const int j0 = jt * 64;
        __syncthreads(); // prior iter's K/V consumers done
#pragma unroll
        for (int u = 0; u < 2; ++u) {
            int t = wave * 2 + u;
            async_cp16(&Ks[t * 8][0], Kg + (size_t)(j0 + t * 8 + lr) * 64 + lsw * 8);
            async_cp16(&Vt[t * 8][0], VT + (size_t)(t * 8 + lr) * S + j0 + lsw * 8);
        }
        __syncthreads(); // drains vmcnt

        // S = Q K^T (Q pre-scaled by 1/8)
        f32x4 sc[4];
#pragma unroll
        for (int nt = 0; nt < 4; ++nt) {
            int R = nt * 16 + l16;
            sc[nt] = __builtin_amdgcn_mfma_f32_16x16x32_bf16(
                qf[0], ld8(&Ks[R][(quad ^ (R & 7)) * 8]), z, 0, 0, 0);
            sc[nt] = __builtin_amdgcn_mfma_f32_16x16x32_bf16(
                qf[1], ld8(&Ks[R][((4 + quad) ^ (R & 7)) * 8]), sc[nt], 0, 0, 0);
        }
        bool need_mask = (j0 + 63 > qrow);
        if (need_mask) {
#pragma unroll
            for (int nt = 0; nt < 4; ++nt)
#pragma unroll
                for (int r = 0; r < 4; ++r)
                    if (j0 + nt * 16 + l16 > qrow + quad * 4 + r) sc[nt][r] = -1e30f;
        }

        // online softmax over 16-lane quad-groups
        float tm[4];
#pragma unroll
        for (int r = 0; r < 4; ++r)
            tm[r] = fmaxf(fmaxf(sc[0][r], sc[1][r]), fmaxf(sc[2][r], sc[3][r]));
#pragma unroll
        for (int msk = 1; msk < 16; msk <<= 1)
#pragma unroll
            for (int r = 0; r < 4; ++r) tm[r] = fmaxf(tm[r], __shfl_xor(tm[r], msk));
        float alpha[4], ts[4];
#pragma unroll
        for (int r = 0; r < 4; ++r) {
            float mn = fmaxf(m_run[r], tm[r]);
            alpha[r] = __expf(m_run[r] - mn);
            m_run[r] = mn;
            ts[r] = 0.f;
        }
#pragma unroll
        for (int nt = 0; nt < 4; ++nt)
#pragma unroll
            for (int r = 0; r < 4; ++r) {
                float p = __expf(sc[nt][r] - m_run[r]);
                sc[nt][r] = p;
                ts[r] += p;
            }
#pragma unroll
        for (int msk = 1; msk < 16; msk <<= 1)
#pragma unroll
            for (int r = 0; r < 4; ++r) ts[r] += __shfl_xor(ts[r], msk);
#pragma unroll
        for (int r = 0; r < 4; ++r) l_run[r] = l_run[r] * alpha[r] + ts[r];

        // P -> LDS (wave-private; no barrier needed)
#pragma unroll
        for (int nt = 0; nt < 4; ++nt)
#pragma unroll
            for (int r = 0; r < 4; ++r)
                Ps[wave][quad * 4 + r][nt * 16 + l16] = __float2bfloat16(sc[nt][r]);

        // O = O*alpha + P V
#pragma unroll
        for (int dt = 0; dt < 4; ++dt)
#pragma unroll
            for (int r = 0; r < 4; ++r) of[dt][r] *= alpha[r];
        short8 pf[2];
#pragma unroll
        for (int kc = 0; kc < 2; ++kc) pf[kc] = ld8(&Ps[wave][l16][kc * 32 + quad * 8]);
#pragma unroll
        for (int dt = 0; dt < 4; ++dt) {
            int R = dt * 16 + l16;
            of[dt] = __builtin_amdgcn_mfma_f32_16x16x32_bf16(
                pf[0], ld8(&Vt[R][(quad ^ (R & 7)) * 8]), of[dt], 0, 0, 0);
            of[dt] = __builtin_amdgcn_mfma_f32_16x16x32_bf16(
                pf[1], ld8(&Vt[R][((4 + quad) ^ (R & 7)) * 8]), of[dt], 0, 0, 0);
        }
    }

    // partials at slot (s, h)
    float* Op = Opart + ((size_t)s * 16 + h) * 4096;
#pragma unroll
    for (int dt = 0; dt < 4; ++dt)
#pragma unroll
        for (int r = 0; r < 4; ++r) {
            int row = wave * 16 + quad * 4 + r;
            Op[row * 64 + dt * 16 + l16] = of[dt][r];
        }
    if (l16 == 0) {
        float* ML = MLpart + ((size_t)s * 16 + h) * 128;
#pragma unroll
        for (int r = 0; r < 4; ++r) {
            int row = wave * 16 + quad * 4 + r;
            ML[row] = m_run[r];
            ML[64 + row] = l_run[r];
        }
    }
}

// ---------------------------------------------------------------------------
// Merge <=4 partials per (q-tile i, head h) -> attn bf16 [S,1024] at (s,h*64+d).
__global__ void flash_merge_kernel(const float* __restrict__ Opart,
                                   const float* __restrict__ MLpart,
                                   bf16* __restrict__ attn) {
    const int i = blockIdx.x, h = blockIdx.y;
    const int nch = (i >> 3) + 1; // 1..4 chunks
    const int tid = threadIdx.x;
    const int row = tid >> 2, cg = (tid & 3) * 16;

    float m[4], l[4];
    for (int cc = 0; cc < nch; ++cc) {
        int s = (cc == 0) ? i : (cc == 1) ? 24 + i : (cc == 2) ? 40 + i : 48 + i;
        const float* ML = MLpart + ((size_t)s * 16 + h) * 128;
        m[cc] = ML[row];
        l[cc] = ML[64 + row];
    }
    float M = m[0];
    for (int cc = 1; cc < nch; ++cc) M = fmaxf(M, m[cc]);
    float L = 0.f, w[4];
    for (int cc = 0; cc < nch; ++cc) {
        w[cc] = __expf(m[cc] - M);
        L += l[cc] * w[cc];
    }
    float inv = 1.f / L;

    float o[16];
#pragma unroll
    for (int j = 0; j < 16; ++j) o[j] = 0.f;
    for (int cc = 0; cc < nch; ++cc) {
        int s = (cc == 0) ? i : (cc == 1) ? 24 + i : (cc == 2) ? 40 + i : 48 + i;
        const float* Op = Opart + ((size_t)s * 16 + h) * 4096 + row * 64 + cg;
#pragma unroll
        for (int j = 0; j < 16; ++j) o[j] += Op[j] * w[cc];
    }
    bf16* dst = attn + (size_t)(i * 64 + row) * 1024 + h * 64 + cg;
#pragma unroll
    for (int j = 0; j < 16; ++j) dst[j] = __float2bfloat16(o[j] * inv);
}

// ---------------------------------------------------------------------------
extern "C" void kernel_launch(void* const* d_in, const int* in_sizes, int n_in,
                              void* d_out, int out_size, void* d_ws, size_t ws_size,
                              hipStream_t stream) {
    const int S = 2048, E = 1024, D = 64;

    const float* hs = (const float*)d_in[0];
    const float* Wq = (const float*)d_in[2];
    const float* bq = (const float*)d_in[3];
    const float* Wk = (const float*)d_in[4];
    const float* bk = (const float*)d_in[5];
    const float* Wv = (const float*)d_in[6];
    const float* bv = (const float*)d_in[7];
    const float* Wo = (const float*)d_in[8];
    const float* bo = (const float*)d_in[9];
    float* out = (float*)d_out;

    bf16* ws = (bf16*)d_ws;
    bf16* hsb = ws;                       // S*E
    bf16* wqb = hsb + (size_t)S * E;      // E*E
    bf16* wkb = wqb + (size_t)E * E;      // D*E
    bf16* wvb = wkb + (size_t)D * E;      // D*E
    bf16* wob = wvb + (size_t)D * E;      // E*E
    bf16* q = wob + (size_t)E * E;        // S*E (holds Q * 1/8)
    bf16* kbuf = q + (size_t)S * E;       // S*D
    bf16* vt = kbuf + (size_t)S * D;      // D*S (transposed)
    bf16* attn = vt + (size_t)S * D;      // S*E
    float* Opart = (float*)(attn + (size_t)S * E); // 1280 slots * 4096 f32 (21 MB)
    float* MLpart = Opart + (size_t)1280 * 4096;   // 1280 * 128 f32 (0.66 MB)

    dim3 blk(256);
    cast_kernel<<<512, blk, 0, stream>>>(hs, hsb, S * E,
                                         Wq, wqb, E * E,
                                         Wk, wkb, D * E,
                                         Wv, wvb, D * E,
                                         Wo, wob, E * E);
    // projections (Q pre-scaled by 1/8 = 1/sqrt(D), fp32-exact)
    gemm_bt_mfma<bf16><<<dim3(E / 64, S / 128), blk, 0, stream>>>(hsb, wqb, bq, q, S, E, E, 0, 0.125f);
    gemm_bt_mfma<bf16><<<dim3(1, S / 128), blk, 0, stream>>>(hsb, wkb, bk, kbuf, S, D, E, 0, 1.f);
    gemm_bt_mfma<bf16><<<dim3(1, S / 128), blk, 0, stream>>>(hsb, wvb, bv, vt, S, D, E, 1, 1.f);
    // attention: balanced k-split phase A + merge
    flash_mfma_kernel<<<dim3(80, 16), blk, 0, stream>>>(q, kbuf, vt, Opart, MLpart, S);
    flash_merge_kernel<<<dim3(32, 16), blk, 0, stream>>>(Opart, MLpart, attn);
    // output projection (fp32 out)
    gemm_bt_mfma<float><<<dim3(E / 64, S / 128), blk, 0, stream>>>(attn, wob, bo, out, S, E, E, 0, 1.f);
}

// Round 6
// 169.602 us; speedup vs baseline: 12.1412x; 1.2338x over previous
//
#include <hip/hip_runtime.h>
#include <hip/hip_bf16.h>

typedef __hip_bfloat16 bf16;
typedef __attribute__((ext_vector_type(8))) short short8;   // 8 bf16 = 4 VGPRs
typedef __attribute__((ext_vector_type(4))) float f32x4;    // MFMA C/D frag

__device__ __forceinline__ short8 ld8(const void* p) { return *(const short8*)p; }
__device__ __forceinline__ void st8(void* p, short8 v) { *(short8*)p = v; }

// async global->LDS, 16B per lane: LDS dest = (wave-uniform) base + lane*16
__device__ __forceinline__ void async_cp16(bf16* lds, const bf16* g) {
    __builtin_amdgcn_global_load_lds(
        (const __attribute__((address_space(1))) unsigned int*)g,
        (__attribute__((address_space(3))) unsigned int*)lds, 16, 0, 0);
}

struct bf4 { bf16 a, b, c, d; };

// ---------------------------------------------------------------------------
__global__ void cast_kernel(const float* __restrict__ s0, bf16* __restrict__ d0, int n0_,
                            const float* __restrict__ s1, bf16* __restrict__ d1, int n1_,
                            const float* __restrict__ s2, bf16* __restrict__ d2, int n2_,
                            const float* __restrict__ s3, bf16* __restrict__ d3, int n3_,
                            const float* __restrict__ s4, bf16* __restrict__ d4, int n4_) {
    const float* srcs[5] = {s0, s1, s2, s3, s4};
    bf16* dsts[5] = {d0, d1, d2, d3, d4};
    int ns[5] = {n0_, n1_, n2_, n3_, n4_};
    int stride = gridDim.x * blockDim.x;
    int t0 = blockIdx.x * blockDim.x + threadIdx.x;
#pragma unroll
    for (int a = 0; a < 5; ++a) {
        const float4* src = (const float4*)srcs[a];
        bf4* dst = (bf4*)dsts[a];
        int n4 = ns[a] >> 2;
        for (int i = t0; i < n4; i += stride) {
            float4 v = src[i];
            bf4 o = {__float2bfloat16(v.x), __float2bfloat16(v.y),
                     __float2bfloat16(v.z), __float2bfloat16(v.w)};
            dst[i] = o;
        }
    }
}

// ---------------------------------------------------------------------------
// Fused Q/K/V projection. A = hsb [M,K]. N-tiles: 0..15 -> Q (scaled 1/8),
// 16 -> K, 17 -> V (stored transposed). Tile 128x64, BK=64, 4 waves.
__global__ void qkv_proj_kernel(const bf16* __restrict__ A,
                                const bf16* __restrict__ Wq, const bf16* __restrict__ Wk,
                                const bf16* __restrict__ Wv,
                                const float* __restrict__ bq, const float* __restrict__ bk,
                                const float* __restrict__ bv,
                                bf16* __restrict__ qo, bf16* __restrict__ ko,
                                bf16* __restrict__ vto, int M, int K) {
    __shared__ __align__(16) bf16 As[128][64];
    __shared__ __align__(16) bf16 Bs[64][64];
    const int nt = blockIdx.x;
    const bf16* W;
    const float* bias;
    int mode, nw0;
    if (nt < 16)      { W = Wq; bias = bq; mode = 0; nw0 = nt * 64; }
    else if (nt == 16){ W = Wk; bias = bk; mode = 1; nw0 = 0; }
    else              { W = Wv; bias = bv; mode = 2; nw0 = 0; }

    const int tid = threadIdx.x;
    const int wave = tid >> 6, lane = tid & 63;
    const int l16 = lane & 15, quad = lane >> 4;
    const int m0 = blockIdx.y * 128;
    const int lr = lane >> 3, lsw = (lane & 7) ^ (lr & 7);

    f32x4 acc[2][4];
    const f32x4 z = {0.f, 0.f, 0.f, 0.f};
#pragma unroll
    for (int mi = 0; mi < 2; ++mi)
#pragma unroll
        for (int ni = 0; ni < 4; ++ni) acc[mi][ni] = z;

    for (int k0 = 0; k0 < K; k0 += 64) {
#pragma unroll
        for (int u = 0; u < 4; ++u) {
            int t = wave * 4 + u;
            async_cp16(&As[t * 8][0], A + (size_t)(m0 + t * 8 + lr) * K + k0 + lsw * 8);
        }
#pragma unroll
        for (int u = 0; u < 2; ++u) {
            int t = wave * 2 + u;
            async_cp16(&Bs[t * 8][0], W + (size_t)(nw0 + t * 8 + lr) * K + k0 + lsw * 8);
        }
        __syncthreads();

        short8 af[2][2], bfr[2][4];
#pragma unroll
        for (int mi = 0; mi < 2; ++mi)
#pragma unroll
            for (int kc = 0; kc < 2; ++kc) {
                int R = wave * 32 + mi * 16 + l16;
                int g = kc * 4 + quad;
                af[mi][kc] = ld8(&As[R][(g ^ (R & 7)) * 8]);
            }
#pragma unroll
        for (int ni = 0; ni < 4; ++ni)
#pragma unroll
            for (int kc = 0; kc < 2; ++kc) {
                int r = ni * 16 + l16;
                int g = kc * 4 + quad;
                bfr[kc][ni] = ld8(&Bs[r][(g ^ (r & 7)) * 8]);
            }
#pragma unroll
        for (int kc = 0; kc < 2; ++kc)
#pragma unroll
            for (int mi = 0; mi < 2; ++mi)
#pragma unroll
                for (int ni = 0; ni < 4; ++ni)
                    acc[mi][ni] = __builtin_amdgcn_mfma_f32_16x16x32_bf16(
                        af[mi][kc], bfr[kc][ni], acc[mi][ni], 0, 0, 0);
        __syncthreads();
    }

#pragma unroll
    for (int mi = 0; mi < 2; ++mi)
#pragma unroll
        for (int ni = 0; ni < 4; ++ni)
#pragma unroll
            for (int r = 0; r < 4; ++r) {
                int row = m0 + wave * 32 + mi * 16 + quad * 4 + r;
                int col = ni * 16 + l16; // 0..63 within tile
                float v = acc[mi][ni][r] + bias[nw0 + col];
                if (mode == 0)
                    qo[(size_t)row * 1024 + nt * 64 + col] = __float2bfloat16(v * 0.125f);
                else if (mode == 1)
                    ko[(size_t)row * 64 + col] = __float2bfloat16(v);
                else
                    vto[(size_t)col * M + row] = __float2bfloat16(v);
            }
}

// ---------------------------------------------------------------------------
// C[M,N] = A[M,K](bf16) @ W[N,K](bf16)^T + bias (fp32 out). 128x64 tile.
__global__ void gemm_bt_mfma(const bf16* __restrict__ A, const bf16* __restrict__ W,
                             const float* __restrict__ bias, float* __restrict__ C,
                             int M, int N, int K) {
    __shared__ __align__(16) bf16 As[128][64];
    __shared__ __align__(16) bf16 Bs[64][64];
    const int tid = threadIdx.x;
    const int wave = tid >> 6, lane = tid & 63;
    const int l16 = lane & 15, quad = lane >> 4;
    const int m0 = blockIdx.y * 128, n0 = blockIdx.x * 64;
    const int lr = lane >> 3, lsw = (lane & 7) ^ (lr & 7);

    f32x4 acc[2][4];
    const f32x4 z = {0.f, 0.f, 0.f, 0.f};
#pragma unroll
    for (int mi = 0; mi < 2; ++mi)
#pragma unroll
        for (int ni = 0; ni < 4; ++ni) acc[mi][ni] = z;

    for (int k0 = 0; k0 < K; k0 += 64) {
#pragma unroll
        for (int u = 0; u < 4; ++u) {
            int t = wave * 4 + u;
            async_cp16(&As[t * 8][0], A + (size_t)(m0 + t * 8 + lr) * K + k0 + lsw * 8);
        }
#pragma unroll
        for (int u = 0; u < 2; ++u) {
            int t = wave * 2 + u;
            async_cp16(&Bs[t * 8][0], W + (size_t)(n0 + t * 8 + lr) * K + k0 + lsw * 8);
        }
        __syncthreads();

        short8 af[2][2], bfr[2][4];
#pragma unroll
        for (int mi = 0; mi < 2; ++mi)
#pragma unroll
            for (int kc = 0; kc < 2; ++kc) {
                int R = wave * 32 + mi * 16 + l16;
                int g = kc * 4 + quad;
                af[mi][kc] = ld8(&As[R][(g ^ (R & 7)) * 8]);
            }
#pragma unroll
        for (int ni = 0; ni < 4; ++ni)
#pragma unroll
            for (int kc = 0; kc < 2; ++kc) {
                int r = ni * 16 + l16;
                int g = kc * 4 + quad;
                bfr[kc][ni] = ld8(&Bs[r][(g ^ (r & 7)) * 8]);
            }
#pragma unroll
        for (int kc = 0; kc < 2; ++kc)
#pragma unroll
            for (int mi = 0; mi < 2; ++mi)
#pragma unroll
                for (int ni = 0; ni < 4; ++ni)
                    acc[mi][ni] = __builtin_amdgcn_mfma_f32_16x16x32_bf16(
                        af[mi][kc], bfr[kc][ni], acc[mi][ni], 0, 0, 0);
        __syncthreads();
    }

#pragma unroll
    for (int mi = 0; mi < 2; ++mi)
#pragma unroll
        for (int ni = 0; ni < 4; ++ni)
#pragma unroll
            for (int r = 0; r < 4; ++r) {
                int row = m0 + wave * 32 + mi * 16 + quad * 4 + r;
                int col = n0 + ni * 16 + l16;
                C[(size_t)row * N + col] = acc[mi][ni][r] + bias[col];
            }
}

// ---------------------------------------------------------------------------
// Flash causal MQA phase A. Chunk = 8 k-tiles (512 keys); 80 slots/head.
// Double-buffered K/V (one barrier per iter, prefetch overlaps compute);
// l-sum folded into MFMA via ones-column B-fragment (valid on l16==0 lanes).
__global__ void flash_mfma_kernel(const bf16* __restrict__ Q, const bf16* __restrict__ Kg,
                                  const bf16* __restrict__ VT,
                                  float* __restrict__ Opart, float* __restrict__ MLpart,
                                  int S) {
    const int s = blockIdx.x;
    int i, c;
    if (s < 32)      { c = 0; i = s; }
    else if (s < 56) { c = 1; i = s - 24; }
    else if (s < 72) { c = 2; i = s - 40; }
    else             { c = 3; i = s - 48; }

    __shared__ __align__(16) bf16 Ks[2][64][64]; // 16 KB, XOR-swizzled
    __shared__ __align__(16) bf16 Vt[2][64][64]; // 16 KB, XOR-swizzled
    __shared__ bf16 Ps[4][16][68];               // 8.7 KB, stride 68

    const int h = blockIdx.y;
    const int q0 = i * 64;
    const int tid = threadIdx.x;
    const int wave = tid >> 6, lane = tid & 63;
    const int l16 = lane & 15, quad = lane >> 4;
    const int lr = lane >> 3, lsw = (lane & 7) ^ (lr & 7);
    const int qrow = q0 + wave * 16;

    short8 qf[2];
#pragma unroll
    for (int kc = 0; kc < 2; ++kc)
        qf[kc] = ld8(Q + (size_t)(qrow + l16) * 1024 + h * 64 + kc * 32 + quad * 8);

    // ones B-frag: column n=0 (l16==0 lanes) = 1.0, else 0 -> P row-sums
    short8 onesf;
    {
        short o = (l16 == 0) ? (short)0x3F80 : (short)0;
        onesf[0]=o; onesf[1]=o; onesf[2]=o; onesf[3]=o;
        onesf[4]=o; onesf[5]=o; onesf[6]=o; onesf[7]=o;
    }

    f32x4 of[4];
    const f32x4 z = {0.f, 0.f, 0.f, 0.f};
#pragma unroll
    for (int dt = 0; dt < 4; ++dt) of[dt] = z;
    float m_run[4], l_run[4];
#pragma unroll
    for (int r = 0; r < 4; ++r) { m_run[r] = -1e30f; l_run[r] = 0.f; }

    const int jt0 = c * 8;
    const int jt1 = min(c * 8 + 8, i + 1);

    // prologue: stage jt0 into buf 0
    {
        const int j0 = jt0 * 64;
#pragma unroll
        for (int u = 0; u < 2; ++u) {
            int t = wave * 2 + u;
            async_cp16(&Ks[0][t * 8][0], Kg + (size_t)(j0 + t * 8 + lr) * 64 + lsw * 8);
            async_cp16(&Vt[0][t * 8][0], VT + (size_t)(t * 8 + lr) * S + j0 + lsw * 8);
        }
    }

    int buf = 0;
    for (int jt = jt0; jt < jt1; ++jt, buf ^= 1) {
        __syncthreads(); // staged data for jt visible (drains vmcnt/lgkm)
        if (jt + 1 < jt1) { // prefetch next tile into other buffer
            const int j0n = (jt + 1) * 64;
#pragma unroll
            for (int u = 0; u < 2; ++u) {
                int t = wave * 2 + u;
                async_cp16(&Ks[buf ^ 1][t * 8][0], Kg + (size_t)(j0n + t * 8 + lr) * 64 + lsw * 8);
                async_cp16(&Vt[buf ^ 1][t * 8][0], VT + (size_t)(t * 8 + lr) * S + j0n + lsw * 8);
            }
        }
        const int j0 = jt * 64;

        // S = Q K^T (Q pre-scaled by 1/8)
        f32x4 sc[4];
#pragma unroll
        for (int nt = 0; nt < 4; ++nt) {
            int R = nt * 16 + l16;
            sc[nt] = __builtin_amdgcn_mfma_f32_16x16x32_bf16(
                qf[0], ld8(&Ks[buf][R][(quad ^ (R & 7)) * 8]), z, 0, 0, 0);
            sc[nt] = __builtin_amdgcn_mfma_f32_16x16x32_bf16(
                qf[1], ld8(&Ks[buf][R][((4 + quad) ^ (R & 7)) * 8]), sc[nt], 0, 0, 0);
        }
        bool need_mask = (j0 + 63 > qrow);
        if (need_mask) {
#pragma unroll
            for (int nt = 0; nt < 4; ++nt)
#pragma unroll
                for (int r = 0; r < 4; ++r)
                    if (j0 + nt * 16 + l16 > qrow + quad * 4 + r) sc[nt][r] = -1e30f;
        }

        // row max via shfl over the 16-lane quad-group
        float tm[4];
#pragma unroll
        for (int r = 0; r < 4; ++r)
            tm[r] = fmaxf(fmaxf(sc[0][r], sc[1][r]), fmaxf(sc[2][r], sc[3][r]));
#pragma unroll
        for (int msk = 1; msk < 16; msk <<= 1)
#pragma unroll
            for (int r = 0; r < 4; ++r) tm[r] = fmaxf(tm[r], __shfl_xor(tm[r], msk));
        float alpha[4];
#pragma unroll
        for (int r = 0; r < 4; ++r) {
            float mn = fmaxf(m_run[r], tm[r]);
            alpha[r] = __expf(m_run[r] - mn);
            m_run[r] = mn;
        }
        // P = exp(S - m), pack to LDS (wave-private, no barrier)
#pragma unroll
        for (int nt = 0; nt < 4; ++nt)
#pragma unroll
            for (int r = 0; r < 4; ++r)
                Ps[wave][quad * 4 + r][nt * 16 + l16] =
                    __float2bfloat16(__expf(sc[nt][r] - m_run[r]));

#pragma unroll
        for (int dt = 0; dt < 4; ++dt)
#pragma unroll
            for (int r = 0; r < 4; ++r) of[dt][r] *= alpha[r];
        short8 pf[2];
#pragma unroll
        for (int kc = 0; kc < 2; ++kc) pf[kc] = ld8(&Ps[wave][l16][kc * 32 + quad * 8]);

        // l-sum via MFMA with ones column (result valid on l16==0 lanes)
        f32x4 lsum = __builtin_amdgcn_mfma_f32_16x16x32_bf16(pf[0], onesf, z, 0, 0, 0);
        lsum = __builtin_amdgcn_mfma_f32_16x16x32_bf16(pf[1], onesf, lsum, 0, 0, 0);
#pragma unroll
        for (int r = 0; r < 4; ++r) l_run[r] = l_run[r] * alpha[r] + lsum[r];

        // O += P V
#pragma unroll
        for (int dt = 0; dt < 4; ++dt) {
            int R = dt * 16 + l16;
            of[dt] = __builtin_amdgcn_mfma_f32_16x16x32_bf16(
                pf[0], ld8(&Vt[buf][R][(quad ^ (R & 7)) * 8]), of[dt], 0, 0, 0);
            of[dt] = __builtin_amdgcn_mfma_f32_16x16x32_bf16(
                pf[1], ld8(&Vt[buf][R][((4 + quad) ^ (R & 7)) * 8]), of[dt], 0, 0, 0);
        }
    }

    // partials at slot (s, h)
    float* Op = Opart + ((size_t)s * 16 + h) * 4096;
#pragma unroll
    for (int dt = 0; dt < 4; ++dt)
#pragma unroll
        for (int r = 0; r < 4; ++r) {
            int row = wave * 16 + quad * 4 + r;
            Op[row * 64 + dt * 16 + l16] = of[dt][r];
        }
    if (l16 == 0) {
        float* ML = MLpart + ((size_t)s * 16 + h) * 128;
#pragma unroll
        for (int r = 0; r < 4; ++r) {
            int row = wave * 16 + quad * 4 + r;
            ML[row] = m_run[r];
            ML[64 + row] = l_run[r];
        }
    }
}

// ---------------------------------------------------------------------------
// Merge <=4 partials per (q-tile i, head h) -> attn bf16 [S,1024] at (s,h*64+d).
__global__ void flash_merge_kernel(const float* __restrict__ Opart,
                                   const float* __restrict__ MLpart,
                                   bf16* __restrict__ attn) {
    const int i = blockIdx.x, h = blockIdx.y;
    const int nch = (i >> 3) + 1; // 1..4 chunks
    const int tid = threadIdx.x;
    const int row = tid >> 2, cg = (tid & 3) * 16;

    float m[4], l[4];
    for (int cc = 0; cc < nch; ++cc) {
        int s = (cc == 0) ? i : (cc == 1) ? 24 + i : (cc == 2) ? 40 + i : 48 + i;
        const float* ML = MLpart + ((size_t)s * 16 + h) * 128;
        m[cc] = ML[row];
        l[cc] = ML[64 + row];
    }
    float M = m[0];
    for (int cc = 1; cc < nch; ++cc) M = fmaxf(M, m[cc]);
    float L = 0.f, w[4];
    for (int cc = 0; cc < nch; ++cc) {
        w[cc] = __expf(m[cc] - M);
        L += l[cc] * w[cc];
    }
    float inv = 1.f / L;

    float o[16];
#pragma unroll
    for (int j = 0; j < 16; ++j) o[j] = 0.f;
    for (int cc = 0; cc < nch; ++cc) {
        int s = (cc == 0) ? i : (cc == 1) ? 24 + i : (cc == 2) ? 40 + i : 48 + i;
        const float* Op = Opart + ((size_t)s * 16 + h) * 4096 + row * 64 + cg;
#pragma unroll
        for (int j = 0; j < 16; ++j) o[j] += Op[j] * w[cc];
    }
    bf16* dst = attn + (size_t)(i * 64 + row) * 1024 + h * 64 + cg;
#pragma unroll
    for (int j = 0; j < 16; ++j) dst[j] = __float2bfloat16(o[j] * inv);
}

// ---------------------------------------------------------------------------
extern "C" void kernel_launch(void* const* d_in, const int* in_sizes, int n_in,
                              void* d_out, int out_size, void* d_ws, size_t ws_size,
                              hipStream_t stream) {
    const int S = 2048, E = 1024, D = 64;

    const float* hs = (const float*)d_in[0];
    const float* Wq = (const float*)d_in[2];
    const float* bq = (const float*)d_in[3];
    const float* Wk = (const float*)d_in[4];
    const float* bk = (const float*)d_in[5];
    const float* Wv = (const float*)d_in[6];
    const float* bv = (const float*)d_in[7];
    const float* Wo = (const float*)d_in[8];
    const float* bo = (const float*)d_in[9];
    float* out = (float*)d_out;

    bf16* ws = (bf16*)d_ws;
    bf16* hsb = ws;                       // S*E
    bf16* wqb = hsb + (size_t)S * E;      // E*E
    bf16* wkb = wqb + (size_t)E * E;      // D*E
    bf16* wvb = wkb + (size_t)D * E;      // D*E
    bf16* wob = wvb + (size_t)D * E;      // E*E
    bf16* q = wob + (size_t)E * E;        // S*E (holds Q * 1/8)
    bf16* kbuf = q + (size_t)S * E;       // S*D
    bf16* vt = kbuf + (size_t)S * D;      // D*S (transposed)
    bf16* attn = vt + (size_t)S * D;      // S*E
    float* Opart = (float*)(attn + (size_t)S * E); // 1280 slots * 4096 f32 (21 MB)
    float* MLpart = Opart + (size_t)1280 * 4096;   // 1280 * 128 f32 (0.66 MB)

    dim3 blk(256);
    cast_kernel<<<512, blk, 0, stream>>>(hs, hsb, S * E,
                                         Wq, wqb, E * E,
                                         Wk, wkb, D * E,
                                         Wv, wvb, D * E,
                                         Wo, wob, E * E);
    // fused Q/K/V projection (Q pre-scaled by 1/8)
    qkv_proj_kernel<<<dim3(18, S / 128), blk, 0, stream>>>(hsb, wqb, wkb, wvb,
                                                           bq, bk, bv,
                                                           q, kbuf, vt, S, E);
    // attention: balanced k-split phase A (dbuf) + merge
    flash_mfma_kernel<<<dim3(80, 16), blk, 0, stream>>>(q, kbuf, vt, Opart, MLpart, S);
    flash_merge_kernel<<<dim3(32, 16), blk, 0, stream>>>(Opart, MLpart, attn);
    // output projection (fp32 out)
    gemm_bt_mfma<<<dim3(E / 64, S / 128), blk, 0, stream>>>(attn, wob, bo, out, S, E, E);
}